// Round 3
// baseline (216.685 us; speedup 1.0000x reference)
//
#include <hip/hip_runtime.h>

// ColorHistogramLoss: B=32, C=3, H=W=512, BINS=64.
// loss = mean | hist(input)/N - hist(target)/N | over 96*64 bins.
//
// R3: LDS atomics are ~1 lane/cycle on gfx950 (R1==R2==75us despite conflict
// counter 4M->0; 3072 ds_add/CU * ~58cyc = 180k cyc = 75us). Replace with
// per-thread EXCLUSIVE byte rows + plain ds_read_i8/add/ds_write_b8 RMW.
// Row stride 68 bytes: bank = (17*t + b/4)%32, 17 coprime 32 -> 32 banks,
// 2 lanes/bank different words = free. |count| <= 32 fits signed char.

#define BINS 64
#define PLANES 96          // B*C
#define PLANE_F4 65536     // 512*512/4
#define SEGS 32            // segments per plane
#define SEG_F4 2048        // PLANE_F4/SEGS
#define TPB 256
#define F4T 8              // SEG_F4/TPB float4 per thread per tensor
#define RSTRIDE 68         // byte row stride (17408 B total, 17 ints/thread init)

__device__ __forceinline__ void bump(signed char* row, float v, int inc) {
    // searchsorted(linspace(-1,1,64), v, 'right')-1 == floor((v+1)*31.5),
    // v < -1 invalid (skip), clamp top to 63.
    int bin = (int)floorf((v + 1.0f) * 31.5f);
    if (bin >= 0) {
        bin = bin > 63 ? 63 : bin;
        row[bin] = (signed char)(row[bin] + inc);   // non-atomic: row is exclusive
    }
}

__global__ __launch_bounds__(TPB, 8) void hist_diff_kernel(
        const float4* __restrict__ in4, const float4* __restrict__ tg4,
        int* __restrict__ gdiff) {
    __shared__ signed char lh[TPB * RSTRIDE];    // [thread][bin], 17408 B
    __shared__ int part[4][BINS];                // per-wave partials, 1 KiB
    const int tid = threadIdx.x;

    // zero init: 4352 ints = 17 per thread
    {
        int* p = (int*)lh;
#pragma unroll
        for (int k = 0; k < (TPB * RSTRIDE / 4) / TPB; ++k) p[tid + k * TPB] = 0;
    }
    __syncthreads();

    const int plane = blockIdx.x >> 5;           // /SEGS
    const int seg   = blockIdx.x & (SEGS - 1);
    const long base = (long)plane * PLANE_F4 + (long)seg * SEG_F4 + tid;
    signed char* row = lh + tid * RSTRIDE;

    float4 a[F4T];
#pragma unroll
    for (int k = 0; k < F4T; ++k) a[k] = in4[base + k * TPB];
#pragma unroll
    for (int k = 0; k < F4T; ++k) {
        bump(row, a[k].x, 1); bump(row, a[k].y, 1);
        bump(row, a[k].z, 1); bump(row, a[k].w, 1);
    }
#pragma unroll
    for (int k = 0; k < F4T; ++k) a[k] = tg4[base + k * TPB];
#pragma unroll
    for (int k = 0; k < F4T; ++k) {
        bump(row, a[k].x, -1); bump(row, a[k].y, -1);
        bump(row, a[k].z, -1); bump(row, a[k].w, -1);
    }

    __syncthreads();
    // merge: wave g, lane j sums bin j over rows g*64..g*64+63.
    // lanes read 64 consecutive bytes per r -> 16 words, 4 lanes/word (read
    // broadcast, conflict-free).
    const int g = tid >> 6, j = tid & 63;
    int s = 0;
#pragma unroll
    for (int r = 0; r < 64; ++r)
        s += lh[(g * 64 + r) * RSTRIDE + j];
    part[g][j] = s;
    __syncthreads();
    if (tid < BINS) {
        int tot = part[0][tid] + part[1][tid] + part[2][tid] + part[3][tid];
        if (tot != 0) atomicAdd(&gdiff[plane * BINS + tid], tot);
    }
}

__global__ __launch_bounds__(TPB) void reduce_abs_kernel(
        const int* __restrict__ gdiff, float* __restrict__ out) {
    int s = 0;
    for (int i = threadIdx.x; i < PLANES * BINS; i += TPB) {
        int v = gdiff[i];
        s += (v < 0) ? -v : v;
    }
#pragma unroll
    for (int off = 32; off > 0; off >>= 1) s += __shfl_down(s, off, 64);
    __shared__ int ws[TPB / 64];
    const int wid  = threadIdx.x >> 6;
    const int lane = threadIdx.x & 63;
    if (lane == 0) ws[wid] = s;
    __syncthreads();
    if (threadIdx.x == 0) {
        int total = 0;
#pragma unroll
        for (int w = 0; w < TPB / 64; ++w) total += ws[w];
        out[0] = (float)total * (1.0f / (262144.0f * 6144.0f));
    }
}

extern "C" void kernel_launch(void* const* d_in, const int* in_sizes, int n_in,
                              void* d_out, int out_size, void* d_ws, size_t ws_size,
                              hipStream_t stream) {
    const float4* inp = (const float4*)d_in[0];
    const float4* tgt = (const float4*)d_in[1];
    int* gdiff = (int*)d_ws;   // 96*64 signed counts, 24 KiB

    hipMemsetAsync(gdiff, 0, PLANES * BINS * sizeof(int), stream);
    hist_diff_kernel<<<PLANES * SEGS, TPB, 0, stream>>>(inp, tgt, gdiff);
    reduce_abs_kernel<<<1, TPB, 0, stream>>>(gdiff, (float*)d_out);
}